// Round 13
// baseline (2864.203 us; speedup 1.0000x reference)
//
#include <hip/hip_runtime.h>
#include <hip/hip_cooperative_groups.h>

typedef _Float16 f16;
typedef _Float16 f16x8 __attribute__((ext_vector_type(8)));
typedef float f32x16 __attribute__((ext_vector_type(16)));

namespace cg = cooperative_groups;

namespace {

constexpr int B_ = 16, T_ = 8, HW = 4096;

__device__ __forceinline__ float sigm(float x)  { return 1.f / (1.f + __expf(-x)); }
__device__ __forceinline__ float ftanh(float x) { return 1.f - 2.f / (1.f + __expf(2.f * x)); }

__device__ __forceinline__ f32x16 zero16() {
  f32x16 v;
#pragma unroll
  for (int i = 0; i < 16; ++i) v[i] = 0.f;
  return v;
}

__device__ __forceinline__ f16x8 zero8h() {
  f16x8 v;
#pragma unroll
  for (int i = 0; i < 8; ++i) v[i] = (f16)0.f;
  return v;
}

// ---------------- weight arrangement ----------------
struct WSet { const float* src; f16* dst; int KC, NCO, CIN; };

__global__ void warr_kernel(WSet s0, WSet s1, WSet s2, WSet s3, WSet s4) {
  WSet s = s0;
  switch (blockIdx.y) { case 1: s = s1; break; case 2: s = s2; break;
                        case 3: s = s3; break; case 4: s = s4; break; default: break; }
  int n = 9 * s.KC * s.NCO * 16;
  int i = blockIdx.x * 256 + threadIdx.x;
  if (i >= n) return;
  int kk = i & 15;
  int t = i >> 4;
  int co = t % s.NCO;
  int dkc = t / s.NCO;
  int kc = dkc % s.KC, dydx = dkc / s.KC;
  int ci = kc * 16 + kk;
  float v = (ci < s.CIN) ? s.src[(co * s.CIN + ci) * 9 + dydx] : 0.f;
  s.dst[i] = (f16)v;
}

// ---------------- positional encoding + add, NHWC f16 out ----------------
__global__ void pe_kernel(const float* __restrict__ xa, const float* __restrict__ midi,
                          const float* __restrict__ w1, const float* __restrict__ b1,
                          const float* __restrict__ w2, const float* __restrict__ b2,
                          f16* __restrict__ xs) {
  int gid = blockIdx.x * 256 + threadIdx.x;
  int half = gid & 1;
  int gpx = gid >> 1;
  int bt = gpx >> 12, gp = gpx & 4095;
  float n0 = -0.5f + midi[bt * 2 + 0] * (1.f / 64.f);
  float n1 = -0.5f + midi[bt * 2 + 1] * (1.f / 64.f);
  float hk[4];
#pragma unroll
  for (int k = 0; k < 4; ++k)
    hk[k] = fmaxf(fmaf(n0, w1[k], fmaf(n1, w1[4 + k], b1[k])), 0.f);
  f16x8 ov;
#pragma unroll
  for (int j = 0; j < 8; ++j) {
    int c = half * 8 + j;
    long p = (long)c * HW + gp;
    float z = b2[p];
#pragma unroll
    for (int k = 0; k < 4; ++k) z = fmaf(hk[k], w2[(long)k * 65536 + p], z);
    ov[j] = (f16)(xa[(long)bt * 65536 + p] + ftanh(z));
  }
  *reinterpret_cast<f16x8*>(xs + (long)gpx * 16 + half * 8) = ov;
}

// ---------------- conv unit (R7 economics: 128px x NCO, 4 waves = 2mg x 2ng) ----
struct ConvDir {
  const f16* x;  long xbs;
  const f16* h;  long hbs;
  const f16* w;
  const float* bias;
  const f16* cin;
  f16* cout;
  float* fout;
  f16* hout; long hobs;
};

constexpr int SMEM_MAX = 180 * 104 * 2;   // >= all ACT sizes and 32KB zbuf

template<int CIN1, int CIN2, int CINPAD, int KCF, int KC, int HST, int HOST,
         bool GATES, int NCO>
__device__ __forceinline__ void conv_unit(const ConvDir& P, int b, int tile, char* smemc)
{
  constexpr int MFRAG = 2;
  constexpr int NF = NCO / 64;
  constexpr int NPH = 9 * KC;
  f16* act = (f16*)smemc;
  f16* zls = (f16*)smemc;

  const int tileY = tile >> 2, tileX = tile & 3;
  const int gy0 = tileY * 8, gx0 = tileX * 16;
  const int tid = threadIdx.x;

  const int lane = tid & 63, wv = tid >> 6;
  const int mg = wv & 1, ng = wv >> 1;
  const int rl = lane & 31;
  const int khalf = (lane >> 5) * 8;
  const int laneA = ((rl >> 4) * 18 + (rl & 15)) * CINPAD + khalf;
  const int laneB = rl * 16 + khalf;
  const f16* __restrict__ wng = P.w + laneB + (long)ng * NF * 32 * 16;
  const f16* __restrict__ arow = act + laneA;

  constexpr int UPX = CIN1 / 8, UPH = CIN2 / 8, UPP = UPX + UPH;
  constexpr int NU  = 180 * UPP;
  constexpr int PER = (NU + 255) / 256;
  const bool have_h = (P.h != nullptr);
  f16x8 sreg[PER];
#pragma unroll
  for (int p = 0; p < PER; ++p) {
    sreg[p] = zero8h();
    int i = tid + p * 256;
    if (i < NU) {
      int px = i / UPP, u = i - px * UPP;
      int py = px / 18, pxx = px - py * 18;
      int gy = gy0 + py - 1, gx = gx0 + pxx - 1;
      if ((unsigned)gy < 64u && (unsigned)gx < 64u && (u < UPX || have_h)) {
        long gp = (long)gy * 64 + gx;
        const f16* src = (u < UPX) ? (P.x + b * P.xbs + gp * CIN1 + u * 8)
                                   : (P.h + b * P.hbs + gp * HST + (u - UPX) * 8);
        sreg[p] = *reinterpret_cast<const f16x8*>(src);
      }
    }
  }

  f16x8 bfr[3][NF];
  f16x8 afr[2][MFRAG];

  auto LBF = [&](int ph) {
    const int slot = ph % 3;
    const int dydx = ph / KC, kc = ph % KC;
#pragma unroll
    for (int nf = 0; nf < NF; ++nf)
      bfr[slot][nf] = *reinterpret_cast<const f16x8*>(
          wng + ((long)(dydx * KCF + kc) * NCO + nf * 32) * 16);
  };
  auto LAF = [&](int ph) {
    const int slot = ph & 1;
    const int dydx = ph / KC, kc = ph % KC;
    const int dy = dydx / 3, dx = dydx % 3;
#pragma unroll
    for (int m = 0; m < MFRAG; ++m)
      afr[slot][m] = *reinterpret_cast<const f16x8*>(
          arow + dx * CINPAD + (((mg * MFRAG + m) * 2 + dy) * 18) * CINPAD + kc * 16);
  };

  LBF(0);
  if (NPH > 1) LBF(1);

#pragma unroll
  for (int p = 0; p < PER; ++p) {
    int i = tid + p * 256;
    if (i < NU) {
      int px = i / UPP, u = i - px * UPP;
      *reinterpret_cast<f16x8*>(act + px * CINPAD + u * 8) = sreg[p];
    }
  }
  __syncthreads();

  if (NPH > 2) LBF(2);

  f32x16 acc[MFRAG][NF];
#pragma unroll
  for (int m = 0; m < MFRAG; ++m)
#pragma unroll
    for (int nf = 0; nf < NF; ++nf) acc[m][nf] = zero16();

  LAF(0);
#pragma unroll
  for (int ph = 0; ph < NPH; ++ph) {
    if (ph + 1 < NPH) LAF(ph + 1);
#pragma unroll
    for (int m = 0; m < MFRAG; ++m)
#pragma unroll
      for (int nf = 0; nf < NF; ++nf)
        acc[m][nf] = __builtin_amdgcn_mfma_f32_32x32x16_f16(
            afr[ph & 1][m], bfr[ph % 3][nf], acc[m][nf], 0, 0, 0);
    if (ph + 3 < NPH) LBF(ph + 3);
  }

  __syncthreads();

  if constexpr (GATES) {
#pragma unroll
    for (int m = 0; m < MFRAG; ++m) {
#pragma unroll
      for (int nf = 0; nf < NF; ++nf) {
        const int col = (ng * NF + nf) * 32 + rl;
        const float bs = P.bias[col];
#pragma unroll
        for (int r = 0; r < 16; ++r) {
          int row = (r & 3) + 8 * (r >> 2) + 4 * (lane >> 5);
          int px = (mg * MFRAG + m) * 32 + row;
          zls[px * 128 + col] = (f16)(acc[m][nf][r] + bs);
        }
      }
    }
    __syncthreads();
#pragma unroll
    for (int it = 0; it < 2; ++it) {
      const int idx = tid + it * 256;
      const int q = idx & 3, px = idx >> 2;
      const int py = px >> 4, pxx = px & 15;
      const long gp = (long)(gy0 + py) * 64 + (gx0 + pxx);
      const f16* zb = zls + px * 128 + q * 8;
      f16x8 zi8 = *reinterpret_cast<const f16x8*>(zb);
      f16x8 zf8 = *reinterpret_cast<const f16x8*>(zb + 32);
      f16x8 zo8 = *reinterpret_cast<const f16x8*>(zb + 64);
      f16x8 zg8 = *reinterpret_cast<const f16x8*>(zb + 96);
      const long cbase = ((long)b * HW + gp) * 32 + q * 8;
      f16x8 c8 = P.cin ? *reinterpret_cast<const f16x8*>(P.cin + cbase) : zero8h();
      f16x8 c2v, h2v;
#pragma unroll
      for (int j = 0; j < 8; ++j) {
        float c2 = sigm((float)zf8[j]) * (float)c8[j]
                 + sigm((float)zi8[j]) * ftanh((float)zg8[j]);
        c2v[j] = (f16)c2;
        h2v[j] = (f16)(sigm((float)zo8[j]) * ftanh(c2));
      }
      if (P.cout) *reinterpret_cast<f16x8*>(P.cout + cbase) = c2v;
      *reinterpret_cast<f16x8*>(P.hout + b * P.hobs + gp * HOST + q * 8) = h2v;
    }
  } else {
#pragma unroll
    for (int m = 0; m < MFRAG; ++m) {
#pragma unroll
      for (int nf = 0; nf < NF; ++nf) {
        const int co = (ng * NF + nf) * 32 + rl;
        const float bs = P.bias[co];
#pragma unroll
        for (int r = 0; r < 16; ++r) {
          int row = (r & 3) + 8 * (r >> 2) + 4 * (lane >> 5);
          int pxt = (mg * MFRAG + m) * 32 + row;
          int py = pxt >> 4, pxx = pxt & 15;
          long gp = (long)(gy0 + py) * 64 + (gx0 + pxx);
          P.fout[((long)b * NCO + co) * HW + gp] = acc[m][nf][r] + bs;
        }
      }
    }
  }
}

// thin wrapper for the non-cooperative fallback path (R7 launch structure)
template<int CIN1, int CIN2, int CINPAD, int KCF, int KC, int HST, int HOST,
         bool GATES, int NCO>
__global__ __launch_bounds__(256, 2)
void conv_mfma(ConvDir p0, ConvDir p1) {
  __shared__ __align__(16) char smem[SMEM_MAX];
  const ConvDir P = blockIdx.y ? p1 : p0;
  conv_unit<CIN1, CIN2, CINPAD, KCF, KC, HST, HOST, GATES, NCO>(
      P, blockIdx.z, blockIdx.x, smem);
}

// ---------------- persistent cooperative chain ----------------
struct ChainArgs {
  const f16* xs; f16* seq0;
  f16 *c0f, *c0b, *c1f, *h1p0, *h1p1, *h1bw;
  const f16 *wt0f, *wt0b, *wt1f, *wt1b, *wtfc;
  const float *b0f, *b0b, *b1f, *b1b, *fcb;
  float* out;
};

__global__ __launch_bounds__(256, 2)
void chain_kernel(ChainArgs A)
{
  __shared__ __align__(16) char smem[SMEM_MAX];
  cg::grid_group grid = cg::this_grid();
  const int blk = blockIdx.x;          // 0..511
  const int b = blk >> 5, tile = blk & 31;

  const long XSB  = (long)T_ * HW * 16;
  const long SLAB = (long)B_ * HW * 64;
  const long SB   = (long)HW * 64;
  const long HB   = (long)HW * 32;

  auto gsync = [&]() { __threadfence(); grid.sync(); __threadfence(); };

  // ---- L0 stage 0 ----
  {
    ConvDir f{A.xs, XSB, nullptr, SB, A.wt0f, A.b0f, nullptr, A.c0f, nullptr, A.seq0, SB};
    conv_unit<16, 32, 56, 3, 1, 64, 64, true, 128>(f, b, tile, smem);
    __syncthreads();
    ConvDir r{A.xs + (long)7 * HW * 16, XSB, nullptr, SB, A.wt0b, A.b0b, nullptr, A.c0b,
              nullptr, A.seq0 + (long)7 * SLAB + 32, SB};
    conv_unit<16, 32, 56, 3, 1, 64, 64, true, 128>(r, b, tile, smem);
  }
  gsync();

  // ---- L0 stages 1..7 ----
  for (int s = 1; s < 8; ++s) {
    int tf = s, tb = 7 - s;
    ConvDir f{A.xs + (long)tf * HW * 16, XSB,
              A.seq0 + (long)(tf - 1) * SLAB, SB,
              A.wt0f, A.b0f, A.c0f, (s == 7) ? nullptr : A.c0f, nullptr,
              A.seq0 + (long)tf * SLAB, SB};
    conv_unit<16, 32, 56, 3, 3, 64, 64, true, 128>(f, b, tile, smem);
    __syncthreads();
    ConvDir r{A.xs + (long)tb * HW * 16, XSB,
              A.seq0 + (long)(tb + 1) * SLAB + 32, SB,
              A.wt0b, A.b0b, A.c0b, (s == 7) ? nullptr : A.c0b, nullptr,
              A.seq0 + (long)tb * SLAB + 32, SB};
    conv_unit<16, 32, 56, 3, 3, 64, 64, true, 128>(r, b, tile, smem);
    gsync();
  }

  // ---- L1 stage 0: fwd step 0 + the single needed bwd step (both zero-state) ----
  {
    ConvDir f{A.seq0, SB, nullptr, HB, A.wt1f, A.b1f, nullptr, A.c1f, nullptr, A.h1p0, HB};
    conv_unit<64, 32, 104, 6, 4, 32, 32, true, 128>(f, b, tile, smem);
    __syncthreads();
    ConvDir r{A.seq0 + (long)7 * SLAB, SB, nullptr, HB, A.wt1b, A.b1b, nullptr, nullptr,
              nullptr, A.h1bw, HB};
    conv_unit<64, 32, 104, 6, 4, 32, 32, true, 128>(r, b, tile, smem);
  }
  gsync();

  // ---- L1 stages 1..7 ----
  for (int s = 1; s < 8; ++s) {
    f16* hprev = (s & 1) ? A.h1p0 : A.h1p1;
    f16* hcur  = (s & 1) ? A.h1p1 : A.h1p0;
    ConvDir f{A.seq0 + (long)s * SLAB, SB, hprev, HB, A.wt1f, A.b1f,
              A.c1f, (s == 7) ? nullptr : A.c1f, nullptr, hcur, HB};
    conv_unit<64, 32, 104, 6, 6, 32, 32, true, 128>(f, b, tile, smem);
    gsync();
  }

  // ---- final conv ----
  {
    ConvDir f{A.h1p1, HB, A.h1bw, HB, A.wtfc, A.fcb, nullptr, nullptr, A.out, nullptr, 0};
    conv_unit<32, 32, 72, 4, 4, 32, 32, false, 64>(f, b, tile, smem);
  }
}

} // namespace

extern "C" void kernel_launch(void* const* d_in, const int* in_sizes, int n_in,
                              void* d_out, int out_size, void* d_ws, size_t ws_size,
                              hipStream_t stream) {
  const float* x_audio = (const float*)d_in[0];
  const float* midi    = (const float*)d_in[1];
  const float* enc_w1  = (const float*)d_in[2];
  const float* enc_b1  = (const float*)d_in[3];
  const float* enc_w2  = (const float*)d_in[4];
  const float* enc_b2  = (const float*)d_in[5];
  const float* w0f = (const float*)d_in[6];
  const float* b0f = (const float*)d_in[7];
  const float* w0b = (const float*)d_in[8];
  const float* b0b = (const float*)d_in[9];
  const float* w1f = (const float*)d_in[10];
  const float* b1f = (const float*)d_in[11];
  const float* w1b = (const float*)d_in[12];
  const float* b1b = (const float*)d_in[13];
  const float* fcw = (const float*)d_in[14];
  const float* fcb = (const float*)d_in[15];

  char* ws = (char*)d_ws;
  size_t off = 0;
  auto alloc = [&](size_t bytes) { char* p = ws + off; off += (bytes + 255) & ~(size_t)255; return p; };

  f16* xs    = (f16*)alloc((size_t)B_ * T_ * HW * 16 * 2);
  f16* seq0  = (f16*)alloc((size_t)T_ * B_ * HW * 64 * 2);
  f16* c0f   = (f16*)alloc((size_t)B_ * HW * 32 * 2);
  f16* c0b   = (f16*)alloc((size_t)B_ * HW * 32 * 2);
  f16* c1f   = (f16*)alloc((size_t)B_ * HW * 32 * 2);
  f16* h1p0  = (f16*)alloc((size_t)B_ * HW * 32 * 2);
  f16* h1p1  = (f16*)alloc((size_t)B_ * HW * 32 * 2);
  f16* h1bw  = (f16*)alloc((size_t)B_ * HW * 32 * 2);
  f16* wt0f  = (f16*)alloc((size_t)9 * 3 * 128 * 16 * 2);
  f16* wt0b  = (f16*)alloc((size_t)9 * 3 * 128 * 16 * 2);
  f16* wt1f  = (f16*)alloc((size_t)9 * 6 * 128 * 16 * 2);
  f16* wt1b  = (f16*)alloc((size_t)9 * 6 * 128 * 16 * 2);
  f16* wtfc  = (f16*)alloc((size_t)9 * 4 * 64 * 16 * 2);

  // 1) arrange weights
  {
    WSet s0{w0f, wt0f, 3, 128, 48}, s1{w0b, wt0b, 3, 128, 48};
    WSet s2{w1f, wt1f, 6, 128, 96}, s3{w1b, wt1b, 6, 128, 96};
    WSet s4{fcw, wtfc, 4, 64, 64};
    warr_kernel<<<dim3(432, 5), 256, 0, stream>>>(s0, s1, s2, s3, s4);
  }

  // 2) positional encoding -> xs
  pe_kernel<<<(B_ * T_ * HW * 2) / 256, 256, 0, stream>>>(
      x_audio, midi, enc_w1, enc_b1, enc_w2, enc_b2, xs);

  // 3) persistent cooperative chain (all 17 conv stages)
  ChainArgs A{xs, seq0, c0f, c0b, c1f, h1p0, h1p1, h1bw,
              wt0f, wt0b, wt1f, wt1b, wtfc,
              b0f, b0b, b1f, b1b, fcb, (float*)d_out};
  void* kargs[] = { &A };
  hipError_t err = hipLaunchCooperativeKernel(
      reinterpret_cast<void*>(chain_kernel), dim3(512), dim3(256), kargs, 0, stream);

  if (err != hipSuccess) {
    // -------- fallback: R7 separate-launch structure --------
    const long XSB  = (long)T_ * HW * 16;
    const long SLAB = (long)B_ * HW * 64;
    const long SB   = (long)HW * 64;
    const long HB   = (long)HW * 32;
    dim3 blk(256);
    {
      ConvDir f{xs, XSB, nullptr, SB, wt0f, b0f, nullptr, c0f, nullptr, seq0, SB};
      ConvDir r{xs + (long)7 * HW * 16, XSB, nullptr, SB, wt0b, b0b, nullptr, c0b,
                nullptr, seq0 + (long)7 * SLAB + 32, SB};
      conv_mfma<16, 32, 56, 3, 1, 64, 64, true, 128>
          <<<dim3(32, 2, 16), blk, 0, stream>>>(f, r);
    }
    for (int s = 1; s < 8; ++s) {
      int tf = s, tb = 7 - s;
      ConvDir f{xs + (long)tf * HW * 16, XSB,
                seq0 + (long)(tf - 1) * SLAB, SB,
                wt0f, b0f, c0f, (s == 7) ? nullptr : c0f, nullptr,
                seq0 + (long)tf * SLAB, SB};
      ConvDir r{xs + (long)tb * HW * 16, XSB,
                seq0 + (long)(tb + 1) * SLAB + 32, SB,
                wt0b, b0b, c0b, (s == 7) ? nullptr : c0b, nullptr,
                seq0 + (long)tb * SLAB + 32, SB};
      conv_mfma<16, 32, 56, 3, 3, 64, 64, true, 128>
          <<<dim3(32, 2, 16), blk, 0, stream>>>(f, r);
    }
    {
      ConvDir f{seq0, SB, nullptr, HB, wt1f, b1f, nullptr, c1f, nullptr, h1p0, HB};
      ConvDir r{seq0 + (long)7 * SLAB, SB, nullptr, HB, wt1b, b1b, nullptr, nullptr,
                nullptr, h1bw, HB};
      conv_mfma<64, 32, 104, 6, 4, 32, 32, true, 128>
          <<<dim3(32, 2, 16), blk, 0, stream>>>(f, r);
    }
    for (int s = 1; s < 8; ++s) {
      f16* hprev = (s & 1) ? h1p0 : h1p1;
      f16* hcur  = (s & 1) ? h1p1 : h1p0;
      ConvDir f{seq0 + (long)s * SLAB, SB, hprev, HB, wt1f, b1f,
                c1f, (s == 7) ? nullptr : c1f, nullptr, hcur, HB};
      conv_mfma<64, 32, 104, 6, 6, 32, 32, true, 128>
          <<<dim3(32, 1, 16), blk, 0, stream>>>(f, f);
    }
    {
      ConvDir f{h1p1, HB, h1bw, HB, wtfc, fcb, nullptr, nullptr, (float*)d_out,
                nullptr, 0};
      conv_mfma<32, 32, 72, 4, 4, 32, 32, false, 64>
          <<<dim3(32, 1, 16), blk, 0, stream>>>(f, f);
    }
  }
}

// Round 14
// 462.756 us; speedup vs baseline: 6.1894x; 6.1894x over previous
//
#include <hip/hip_runtime.h>

typedef _Float16 f16;
typedef _Float16 f16x8 __attribute__((ext_vector_type(8)));
typedef float f32x16 __attribute__((ext_vector_type(16)));

namespace {

constexpr int B_ = 16, T_ = 8, HW = 4096;

__device__ __forceinline__ float sigm(float x)  { return 1.f / (1.f + __expf(-x)); }
__device__ __forceinline__ float ftanh(float x) { return 1.f - 2.f / (1.f + __expf(2.f * x)); }

__device__ __forceinline__ f32x16 zero16() {
  f32x16 v;
#pragma unroll
  for (int i = 0; i < 16; ++i) v[i] = 0.f;
  return v;
}

__device__ __forceinline__ f16x8 zero8h() {
  f16x8 v;
#pragma unroll
  for (int i = 0; i < 8; ++i) v[i] = (f16)0.f;
  return v;
}

// ---------------- weight arrangement ----------------
// src OIHW f32 [NCO][CIN][3][3] -> dst f16 [dydx][kc][co][16]  (k16-contiguous per co)
struct WSet { const float* src; f16* dst; int KC, NCO, CIN; };

__global__ void warr_kernel(WSet s0, WSet s1, WSet s2, WSet s3, WSet s4) {
  WSet s = s0;
  switch (blockIdx.y) { case 1: s = s1; break; case 2: s = s2; break;
                        case 3: s = s3; break; case 4: s = s4; break; default: break; }
  int n = 9 * s.KC * s.NCO * 16;
  int i = blockIdx.x * 256 + threadIdx.x;
  if (i >= n) return;
  int kk = i & 15;
  int t = i >> 4;
  int co = t % s.NCO;
  int dkc = t / s.NCO;
  int kc = dkc % s.KC, dydx = dkc / s.KC;
  int ci = kc * 16 + kk;
  float v = (ci < s.CIN) ? s.src[(co * s.CIN + ci) * 9 + dydx] : 0.f;
  s.dst[i] = (f16)v;
}

// ---------------- positional encoding + add, NHWC f16 out ----------------
// xs layout: [B*T][4096][16] f16
__global__ void pe_kernel(const float* __restrict__ xa, const float* __restrict__ midi,
                          const float* __restrict__ w1, const float* __restrict__ b1,
                          const float* __restrict__ w2, const float* __restrict__ b2,
                          f16* __restrict__ xs) {
  int gid = blockIdx.x * 256 + threadIdx.x;   // one 16B unit (8 channels)
  int half = gid & 1;
  int gpx = gid >> 1;                         // (bt, pixel)
  int bt = gpx >> 12, gp = gpx & 4095;
  float n0 = -0.5f + midi[bt * 2 + 0] * (1.f / 64.f);
  float n1 = -0.5f + midi[bt * 2 + 1] * (1.f / 64.f);
  float hk[4];
#pragma unroll
  for (int k = 0; k < 4; ++k)
    hk[k] = fmaxf(fmaf(n0, w1[k], fmaf(n1, w1[4 + k], b1[k])), 0.f);
  f16x8 ov;
#pragma unroll
  for (int j = 0; j < 8; ++j) {
    int c = half * 8 + j;
    long p = (long)c * HW + gp;
    float z = b2[p];
#pragma unroll
    for (int k = 0; k < 4; ++k) z = fmaf(hk[k], w2[(long)k * 65536 + p], z);
    ov[j] = (f16)(xa[(long)bt * 65536 + p] + ftanh(z));
  }
  *reinterpret_cast<f16x8*>(xs + (long)gpx * 16 + half * 8) = ov;
}

// ---------------- MFMA conv / ConvLSTM step ----------------
// Tile: 128 pixels (8 rows x 16 cols). 4 waves = 2 m-groups x 2 n-groups.
// Wave tile: MFRAG=2 m-frags x NF n-frags -> each B-frag (global) feeds MFRAG
// MFMAs, each A-frag (LDS) feeds NF MFMAs. bf prefetch depth 3, af depth 2.
struct ConvDir {
  const f16* x;  long xbs;   // batch stride (elements)
  const f16* h;  long hbs;
  const f16* w;
  const float* bias;
  const f16* cin;            // f16 c-state in (nullptr => zeros)
  f16* cout;                 // f16 c-state out (nullptr => skip write)
  float* fout;               // !GATES: final f32 NCHW output
  f16* hout; long hobs;
};

template<int CIN1, int CIN2, int CINPAD, int KCF, int KC, int HST, int HOST,
         bool GATES, int NCO>
__global__ __launch_bounds__(256, 2)
void conv_mfma(ConvDir p0, ConvDir p1)
{
  constexpr int MFRAG = 2;                 // m-frags per wave
  constexpr int NF = NCO / 64;             // n-frags per wave (NG=2)
  constexpr int NPH = 9 * KC;              // pipeline phases (CH=1)
  constexpr int ACT_BYTES = 180 * CINPAD * 2;
  constexpr int ZB_BYTES  = GATES ? 128 * 128 * 2 : 0;   // f16 z-buffer [px][4*32]
  constexpr int SMEM = ACT_BYTES > ZB_BYTES ? ACT_BYTES : ZB_BYTES;
  __shared__ __align__(16) char smem[SMEM];
  f16* act = (f16*)smem;
  f16* zls = (f16*)smem;

  const ConvDir P = blockIdx.y ? p1 : p0;
  const int b = blockIdx.z;
  const int tileY = blockIdx.x >> 2, tileX = blockIdx.x & 3;
  const int gy0 = tileY * 8, gx0 = tileX * 16;
  const int tid = threadIdx.x;

  const int lane = tid & 63, wv = tid >> 6;   // wv in [0,4)
  const int mg = wv & 1, ng = wv >> 1;
  const int rl = lane & 31;
  const int khalf = (lane >> 5) * 8;
  const int laneA = ((rl >> 4) * 18 + (rl & 15)) * CINPAD + khalf;   // f16 units
  const int laneB = rl * 16 + khalf;                                  // f16 units
  const f16* __restrict__ wng = P.w + laneB + (long)ng * NF * 32 * 16;
  const f16* __restrict__ arow = act + laneA;

  // ---- staging: load phase (all loads issued back-to-back), then write phase ----
  constexpr int UPX = CIN1 / 8, UPH = CIN2 / 8, UPP = UPX + UPH;
  constexpr int NU  = 180 * UPP;
  constexpr int PER = (NU + 255) / 256;
  const bool have_h = (P.h != nullptr);
  f16x8 sreg[PER];
#pragma unroll
  for (int p = 0; p < PER; ++p) {
    sreg[p] = zero8h();
    int i = tid + p * 256;
    if (i < NU) {
      int px = i / UPP, u = i - px * UPP;
      int py = px / 18, pxx = px - py * 18;
      int gy = gy0 + py - 1, gx = gx0 + pxx - 1;
      if ((unsigned)gy < 64u && (unsigned)gx < 64u && (u < UPX || have_h)) {
        long gp = (long)gy * 64 + gx;
        const f16* src = (u < UPX) ? (P.x + b * P.xbs + gp * CIN1 + u * 8)
                                   : (P.h + b * P.hbs + gp * HST + (u - UPX) * 8);
        sreg[p] = *reinterpret_cast<const f16x8*>(src);
      }
    }
  }

  // ---- pipeline buffers ----
  f16x8 bfr[3][NF];
  f16x8 afr[2][MFRAG];

  auto LBF = [&](int ph) {
    const int slot = ph % 3;
    const int dydx = ph / KC, kc = ph % KC;
#pragma unroll
    for (int nf = 0; nf < NF; ++nf)
      bfr[slot][nf] = *reinterpret_cast<const f16x8*>(
          wng + ((long)(dydx * KCF + kc) * NCO + nf * 32) * 16);
  };
  auto LAF = [&](int ph) {
    const int slot = ph & 1;
    const int dydx = ph / KC, kc = ph % KC;
    const int dy = dydx / 3, dx = dydx % 3;
#pragma unroll
    for (int m = 0; m < MFRAG; ++m)
      afr[slot][m] = *reinterpret_cast<const f16x8*>(
          arow + dx * CINPAD + (((mg * MFRAG + m) * 2 + dy) * 18) * CINPAD + kc * 16);
  };

  // prefetch first two weight phases while staging loads are in flight
  LBF(0);
  if (NPH > 1) LBF(1);

  // staging write phase
#pragma unroll
  for (int p = 0; p < PER; ++p) {
    int i = tid + p * 256;
    if (i < NU) {
      int px = i / UPP, u = i - px * UPP;
      *reinterpret_cast<f16x8*>(act + px * CINPAD + u * 8) = sreg[p];
    }
  }
  __syncthreads();

  if (NPH > 2) LBF(2);

  f32x16 acc[MFRAG][NF];
#pragma unroll
  for (int m = 0; m < MFRAG; ++m)
#pragma unroll
    for (int nf = 0; nf < NF; ++nf) acc[m][nf] = zero16();

  LAF(0);
#pragma unroll
  for (int ph = 0; ph < NPH; ++ph) {
    if (ph + 1 < NPH) LAF(ph + 1);
#pragma unroll
    for (int m = 0; m < MFRAG; ++m)
#pragma unroll
      for (int nf = 0; nf < NF; ++nf)
        acc[m][nf] = __builtin_amdgcn_mfma_f32_32x32x16_f16(
            afr[ph & 1][m], bfr[ph % 3][nf], acc[m][nf], 0, 0, 0);
    if (ph + 3 < NPH) LBF(ph + 3);
  }

  __syncthreads();

  if constexpr (GATES) {
    // phase A (single, all waves disjoint): write z (f16) to zls[128 px][128 co]
#pragma unroll
    for (int m = 0; m < MFRAG; ++m) {
#pragma unroll
      for (int nf = 0; nf < NF; ++nf) {
        const int col = (ng * NF + nf) * 32 + rl;
        const float bs = P.bias[col];
#pragma unroll
        for (int r = 0; r < 16; ++r) {
          int row = (r & 3) + 8 * (r >> 2) + 4 * (lane >> 5);
          int px = (mg * MFRAG + m) * 32 + row;
          zls[px * 128 + col] = (f16)(acc[m][nf][r] + bs);
        }
      }
    }
    __syncthreads();
    // phase B: vectorized gates; item -> (px = idx>>2, hid chunk q = idx&3)
#pragma unroll
    for (int it = 0; it < 2; ++it) {
      const int idx = tid + it * 256;
      const int q = idx & 3, px = idx >> 2;
      const int py = px >> 4, pxx = px & 15;
      const long gp = (long)(gy0 + py) * 64 + (gx0 + pxx);
      const f16* zb = zls + px * 128 + q * 8;
      f16x8 zi8 = *reinterpret_cast<const f16x8*>(zb);
      f16x8 zf8 = *reinterpret_cast<const f16x8*>(zb + 32);
      f16x8 zo8 = *reinterpret_cast<const f16x8*>(zb + 64);
      f16x8 zg8 = *reinterpret_cast<const f16x8*>(zb + 96);
      const long cbase = ((long)b * HW + gp) * 32 + q * 8;
      f16x8 c8 = P.cin ? *reinterpret_cast<const f16x8*>(P.cin + cbase) : zero8h();
      f16x8 c2v, h2v;
#pragma unroll
      for (int j = 0; j < 8; ++j) {
        float c2 = sigm((float)zf8[j]) * (float)c8[j]
                 + sigm((float)zi8[j]) * ftanh((float)zg8[j]);
        c2v[j] = (f16)c2;
        h2v[j] = (f16)(sigm((float)zo8[j]) * ftanh(c2));
      }
      if (P.cout) *reinterpret_cast<f16x8*>(P.cout + cbase) = c2v;
      *reinterpret_cast<f16x8*>(P.hout + b * P.hobs + gp * HOST + q * 8) = h2v;
    }
  } else {
    // final conv: direct f32 NCHW store
#pragma unroll
    for (int m = 0; m < MFRAG; ++m) {
#pragma unroll
      for (int nf = 0; nf < NF; ++nf) {
        const int co = (ng * NF + nf) * 32 + rl;
        const float bs = P.bias[co];
#pragma unroll
        for (int r = 0; r < 16; ++r) {
          int row = (r & 3) + 8 * (r >> 2) + 4 * (lane >> 5);
          int pxt = (mg * MFRAG + m) * 32 + row;
          int py = pxt >> 4, pxx = pxt & 15;
          long gp = (long)(gy0 + py) * 64 + (gx0 + pxx);
          P.fout[((long)b * NCO + co) * HW + gp] = acc[m][nf][r] + bs;
        }
      }
    }
  }
}

} // namespace

extern "C" void kernel_launch(void* const* d_in, const int* in_sizes, int n_in,
                              void* d_out, int out_size, void* d_ws, size_t ws_size,
                              hipStream_t stream) {
  const float* x_audio = (const float*)d_in[0];
  const float* midi    = (const float*)d_in[1];
  const float* enc_w1  = (const float*)d_in[2];
  const float* enc_b1  = (const float*)d_in[3];
  const float* enc_w2  = (const float*)d_in[4];
  const float* enc_b2  = (const float*)d_in[5];
  const float* w0f = (const float*)d_in[6];
  const float* b0f = (const float*)d_in[7];
  const float* w0b = (const float*)d_in[8];
  const float* b0b = (const float*)d_in[9];
  const float* w1f = (const float*)d_in[10];
  const float* b1f = (const float*)d_in[11];
  const float* w1b = (const float*)d_in[12];
  const float* b1b = (const float*)d_in[13];
  const float* fcw = (const float*)d_in[14];
  const float* fcb = (const float*)d_in[15];

  char* ws = (char*)d_ws;
  size_t off = 0;
  auto alloc = [&](size_t bytes) { char* p = ws + off; off += (bytes + 255) & ~(size_t)255; return p; };

  f16* xs    = (f16*)alloc((size_t)B_ * T_ * HW * 16 * 2);   // [B*T][4096][16]
  f16* seq0  = (f16*)alloc((size_t)T_ * B_ * HW * 64 * 2);   // [T][B][4096][64]
  f16* c0f   = (f16*)alloc((size_t)B_ * HW * 32 * 2);
  f16* c0b   = (f16*)alloc((size_t)B_ * HW * 32 * 2);
  f16* c1f   = (f16*)alloc((size_t)B_ * HW * 32 * 2);
  f16* h1p0  = (f16*)alloc((size_t)B_ * HW * 32 * 2);
  f16* h1p1  = (f16*)alloc((size_t)B_ * HW * 32 * 2);
  f16* h1bw  = (f16*)alloc((size_t)B_ * HW * 32 * 2);
  f16* wt0f  = (f16*)alloc((size_t)9 * 3 * 128 * 16 * 2);
  f16* wt0b  = (f16*)alloc((size_t)9 * 3 * 128 * 16 * 2);
  f16* wt1f  = (f16*)alloc((size_t)9 * 6 * 128 * 16 * 2);
  f16* wt1b  = (f16*)alloc((size_t)9 * 6 * 128 * 16 * 2);
  f16* wtfc  = (f16*)alloc((size_t)9 * 4 * 64 * 16 * 2);

  // 1) arrange weights (5 sets, one launch)
  {
    WSet s0{w0f, wt0f, 3, 128, 48}, s1{w0b, wt0b, 3, 128, 48};
    WSet s2{w1f, wt1f, 6, 128, 96}, s3{w1b, wt1b, 6, 128, 96};
    WSet s4{fcw, wtfc, 4, 64, 64};
    warr_kernel<<<dim3(432, 5), 256, 0, stream>>>(s0, s1, s2, s3, s4);
  }

  // 2) positional encoding -> xs (NHWC f16)
  pe_kernel<<<(B_ * T_ * HW * 2) / 256, 256, 0, stream>>>(
      x_audio, midi, enc_w1, enc_b1, enc_w2, enc_b2, xs);

  const long XSB  = (long)T_ * HW * 16;   // xs batch stride
  const long SLAB = (long)B_ * HW * 64;   // seq0 time slab
  const long SB   = (long)HW * 64;        // seq0 batch stride
  const long HB   = (long)HW * 32;        // 32-ch batch stride

  dim3 blk(256);

  // 3) layer 0, fwd + bwd merged per step
  {
    // step 0: no h, K = 16 ch (KC=1)
    ConvDir f{xs, XSB, nullptr, SB, wt0f, b0f, nullptr, c0f, nullptr, seq0, SB};
    ConvDir r{xs + (long)7 * HW * 16, XSB, nullptr, SB, wt0b, b0b, nullptr, c0b,
              nullptr, seq0 + (long)7 * SLAB + 32, SB};
    conv_mfma<16, 32, 56, 3, 1, 64, 64, true, 128>
        <<<dim3(32, 2, 16), blk, 0, stream>>>(f, r);
  }
  for (int s = 1; s < 8; ++s) {
    int tf = s, tb = 7 - s;
    ConvDir f{xs + (long)tf * HW * 16, XSB,
              seq0 + (long)(tf - 1) * SLAB, SB,
              wt0f, b0f, c0f, (s == 7) ? nullptr : c0f, nullptr,
              seq0 + (long)tf * SLAB, SB};
    ConvDir r{xs + (long)tb * HW * 16, XSB,
              seq0 + (long)(tb + 1) * SLAB + 32, SB,
              wt0b, b0b, c0b, (s == 7) ? nullptr : c0b, nullptr,
              seq0 + (long)tb * SLAB + 32, SB};
    conv_mfma<16, 32, 56, 3, 3, 64, 64, true, 128>
        <<<dim3(32, 2, 16), blk, 0, stream>>>(f, r);
  }

  // 4) layer 1: step 0 fwd merged with the single needed bwd step (t=7, zero state)
  {
    ConvDir f{seq0, SB, nullptr, HB, wt1f, b1f, nullptr, c1f, nullptr, h1p0, HB};
    ConvDir r{seq0 + 7 * SLAB, SB, nullptr, HB, wt1b, b1b, nullptr, nullptr, nullptr, h1bw, HB};
    conv_mfma<64, 32, 104, 6, 4, 32, 32, true, 128>
        <<<dim3(32, 2, 16), blk, 0, stream>>>(f, r);
  }
  for (int s = 1; s < 8; ++s) {
    f16* hprev = (s & 1) ? h1p0 : h1p1;
    f16* hcur  = (s & 1) ? h1p1 : h1p0;
    ConvDir f{seq0 + (long)s * SLAB, SB, hprev, HB, wt1f, b1f,
              c1f, (s == 7) ? nullptr : c1f, nullptr, hcur, HB};
    conv_mfma<64, 32, 104, 6, 6, 32, 32, true, 128>
        <<<dim3(32, 1, 16), blk, 0, stream>>>(f, f);
  }

  // 5) final conv: concat(h1p1, h1bw) -> d_out f32 NCHW [B][64][64][64]
  {
    ConvDir f{h1p1, HB, h1bw, HB, wtfc, fcb, nullptr, nullptr, (float*)d_out, nullptr, 0};
    conv_mfma<32, 32, 72, 4, 4, 32, 32, false, 64>
        <<<dim3(32, 1, 16), blk, 0, stream>>>(f, f);
  }
}